// Round 6
// baseline (325.581 us; speedup 1.0000x reference)
//
#include <hip/hip_runtime.h>
#include <hip/hip_bf16.h>

#define BATCH 4
#define NPTS  4096
#define NPTS2 4096
#define CIN   128
#define DIM   64
#define KNN   20
#define UPF   2
#define HPOS  64
#define HATT  256
#define MOUT  8192
#define EPSF  1e-5f
#define QPB   3            // queries per attn block
#define BPB   1366         // ceil(4096/3) attn blocks per batch

// front kernel block ranges
#define FB_KNN   1024
#define FB_PKV   (FB_KNN + 256)
#define FB_PQ    (FB_PKV + 256)
#define FB_PACK  (FB_PQ + 128)

typedef _Float16 h16x8 __attribute__((ext_vector_type(8)));
typedef _Float16 h16x4 __attribute__((ext_vector_type(4)));
typedef _Float16 h16x2 __attribute__((ext_vector_type(2)));
typedef float    f32x4 __attribute__((ext_vector_type(4)));

__device__ inline float rdlane(float v, int src) {
  return __int_as_float(__builtin_amdgcn_readlane(__float_as_int(v), src));
}

// Bit-exact distance: explicit fma DAG -> identical value in every use site.
__device__ __forceinline__ float distf(float qn, float m2x, float m2y, float m2z,
                                       float x, float y, float z) {
  float s = __fmaf_rn(x, x, qn);
  s = __fmaf_rn(y, y, s);
  s = __fmaf_rn(z, z, s);
  s = __fmaf_rn(m2x, x, s);
  s = __fmaf_rn(m2y, y, s);
  s = __fmaf_rn(m2z, z, s);
  return s;
}

// ---------------------------------------------------------------------------
// front (unchanged from R15): fused {knn v5, proj_kv, proj_q, pack_weights}.
// ---------------------------------------------------------------------------
__global__ __launch_bounds__(256) void front(
    // knn
    const float* __restrict__ pos1, const float* __restrict__ pos2,
    int* __restrict__ idxout,
    // proj_kv
    const float* __restrict__ key_feat,
    const float* __restrict__ wk, const float* __restrict__ bk,
    const float* __restrict__ wv, const float* __restrict__ bv,
    float* __restrict__ k_t, float* __restrict__ v_t,
    // proj_q
    const float* __restrict__ query,
    const float* __restrict__ wq, const float* __restrict__ bq,
    float* __restrict__ q_t,
    // pack_weights
    const float* __restrict__ aw1, const float* __restrict__ awt,
    const float* __restrict__ pw2,
    const float* __restrict__ ag,  const float* __restrict__ av,
    const float* __restrict__ abt2, const float* __restrict__ am,
    const float* __restrict__ abt,
    const float* __restrict__ pg,  const float* __restrict__ pv,
    const float* __restrict__ pbt, const float* __restrict__ pm,
    const float* __restrict__ ab1, const float* __restrict__ pb1,
    const float* __restrict__ pw1,
    _Float16* __restrict__ aw1h, _Float16* __restrict__ awtP,
    _Float16* __restrict__ pw2h, float* __restrict__ abtX,
    float* __restrict__ ab1f, float* __restrict__ pw1f,
    float* __restrict__ pb1f) {
  __shared__ union {
    struct { float X[CIN][64]; float O[64][65]; } pj;
    struct { int cnt[16]; float dbuf[16][64]; int jbuf[16][64]; } kn;
  } smU;
  const int bid = blockIdx.x;
  const int t   = threadIdx.x;

  if (bid < FB_KNN) {
    // ---------------- knn v5 ----------------
    const int lane = t & 63;
    const int wv   = t >> 6;
    const int b    = bid >> 8;           // 256 blocks per batch
    const int nb   = (bid & 255) * 16;   // 16 queries per block
    const float* p2x = pos2 + (b * 3 + 0) * NPTS2;
    const float* p2y = pos2 + (b * 3 + 1) * NPTS2;
    const float* p2z = pos2 + (b * 3 + 2) * NPTS2;

    float qn[4], m2x[4], m2y[4], m2z[4];
#pragma unroll
    for (int qi = 0; qi < 4; ++qi) {
      int n = nb + wv * 4 + qi;
      float qx = pos1[(b * 3 + 0) * NPTS + n];
      float qy = pos1[(b * 3 + 1) * NPTS + n];
      float qz = pos1[(b * 3 + 2) * NPTS + n];
      qn[qi]  = qx * qx + qy * qy + qz * qz;
      m2x[qi] = -2.0f * qx; m2y[qi] = -2.0f * qy; m2z[qi] = -2.0f * qz;
    }

    float mymin[4] = {3.402823466e38f, 3.402823466e38f,
                      3.402823466e38f, 3.402823466e38f};
    f32x4 cx[4], cy[4], cz[4];
#pragma unroll 1
    for (int c = 0; c < 4; ++c) {
      int base = c * 1024 + lane * 4;
#pragma unroll
      for (int g = 0; g < 4; ++g) {
        cx[g] = *(const f32x4*)(p2x + base + g * 256);
        cy[g] = *(const f32x4*)(p2y + base + g * 256);
        cz[g] = *(const f32x4*)(p2z + base + g * 256);
      }
#pragma unroll
      for (int qi = 0; qi < 4; ++qi)
#pragma unroll
        for (int g = 0; g < 4; ++g)
#pragma unroll
          for (int e = 0; e < 4; ++e) {
            float d = distf(qn[qi], m2x[qi], m2y[qi], m2z[qi],
                            cx[g][e], cy[g][e], cz[g][e]);
            mymin[qi] = fminf(mymin[qi], d);
          }
    }

    float T0[4];
#pragma unroll
    for (int qi = 0; qi < 4; ++qi) {
      float v = mymin[qi];
#pragma unroll
      for (int k = 2; k <= 64; k <<= 1)
#pragma unroll
        for (int jj = k >> 1; jj >= 1; jj >>= 1) {
          float o = __shfl_xor(v, jj);
          bool up = ((lane & k) == 0);
          bool keepmin = (((lane & jj) == 0) == up);
          v = keepmin ? fminf(v, o) : fmaxf(v, o);
        }
      T0[qi] = rdlane(v, 19);
    }

    if (lane < 4) smU.kn.cnt[wv * 4 + lane] = 0;
    // per-wave private buffers; per-wave LDS in-order -> no barrier

#pragma unroll 1
    for (int c = 0; c < 4; ++c) {
      int base = c * 1024 + lane * 4;
#pragma unroll
      for (int g = 0; g < 4; ++g) {
        cx[g] = *(const f32x4*)(p2x + base + g * 256);
        cy[g] = *(const f32x4*)(p2y + base + g * 256);
        cz[g] = *(const f32x4*)(p2z + base + g * 256);
      }
#pragma unroll
      for (int qi = 0; qi < 4; ++qi) {
        const int qq = wv * 4 + qi;
#pragma unroll
        for (int g = 0; g < 4; ++g)
#pragma unroll
          for (int e = 0; e < 4; ++e) {
            float d = distf(qn[qi], m2x[qi], m2y[qi], m2z[qi],
                            cx[g][e], cy[g][e], cz[g][e]);
            if (d <= T0[qi]) {
              int slot = atomicAdd(&smU.kn.cnt[qq], 1);
              if (slot < 64) { smU.kn.dbuf[qq][slot] = d; smU.kn.jbuf[qq][slot] = base + g * 256 + e; }
            }
          }
      }
    }

#pragma unroll 1
    for (int qi = 0; qi < 4; ++qi) {
      const int qq = wv * 4 + qi;
      const int n  = nb + qq;
      const int cnt = smU.kn.cnt[qq];
      if (cnt <= 64) {
        float dk = (lane < cnt) ? smU.kn.dbuf[qq][lane] : 3.402823466e38f;
        int   jk = (lane < cnt) ? smU.kn.jbuf[qq][lane] : 0x7fffffff;
#pragma unroll
        for (int k = 2; k <= 64; k <<= 1) {
#pragma unroll
          for (int jj = k >> 1; jj >= 1; jj >>= 1) {
            float od = __shfl_xor(dk, jj);
            int   oj = __shfl_xor(jk, jj);
            bool mineSm = (dk < od) || (dk == od && jk < oj);
            bool up = ((lane & k) == 0);
            bool keepmin = (((lane & jj) == 0) == up);
            bool takeOther = (keepmin != mineSm);
            dk = takeOther ? od : dk;
            jk = takeOther ? oj : jk;
          }
        }
        if (lane < KNN) idxout[(b * NPTS + n) * KNN + lane] = jk;
      } else {
        float dl = 3.402823466e38f;
        int   il = 0;
        for (int j0 = 0; j0 < NPTS2; j0 += 64) {
          int j = j0 + lane;
          float d = distf(qn[qi], m2x[qi], m2y[qi], m2z[qi], p2x[j], p2y[j], p2z[j]);
          float T = rdlane(dl, 19);
          unsigned long long m = __ballot(d < T);
          while (m) {
            int src = __ffsll(m) - 1;
            m &= m - 1;
            float dd = rdlane(d, src);
            float T2 = rdlane(dl, 19);
            if (dd < T2) {
              int jj2 = j0 + src;
              float pd = __shfl_up(dl, 1);
              int   pi = __shfl_up(il, 1);
              if (dl > dd) {
                if (lane == 0 || pd <= dd) { dl = dd; il = jj2; }
                else                       { dl = pd; il = pi; }
              }
            }
          }
        }
        if (lane < KNN) idxout[(b * NPTS + n) * KNN + lane] = il;
      }
    }
  } else if (bid < FB_PKV) {
    // ---------------- proj_kv ----------------
    const int vb = bid - FB_KNN;
    const int b  = vb >> 6;
    const int n0 = (vb & 63) * 64;
    for (int l = t; l < CIN * 64; l += 256) {
      int c = l >> 6, i = l & 63;
      smU.pj.X[c][i] = key_feat[(b * CIN + c) * NPTS2 + n0 + i];
    }
    __syncthreads();
    const int n_l = t & 63;
    const int w   = __builtin_amdgcn_readfirstlane(t >> 6);
    float acck[16], accv[16];
#pragma unroll
    for (int i = 0; i < 16; ++i) { acck[i] = bk[w * 16 + i]; accv[i] = bv[w * 16 + i]; }
    for (int c = 0; c < CIN; ++c) {
      float xv = smU.pj.X[c][n_l];
#pragma unroll
      for (int i = 0; i < 16; ++i) {
        acck[i] += wk[(w * 16 + i) * CIN + c] * xv;
        accv[i] += wv[(w * 16 + i) * CIN + c] * xv;
      }
    }
#pragma unroll
    for (int i = 0; i < 16; ++i) smU.pj.O[n_l][w * 16 + i] = acck[i];
    __syncthreads();
    for (int l = t; l < 64 * 64; l += 256)
      k_t[(b * NPTS2 + n0 + (l >> 6)) * DIM + (l & 63)] = smU.pj.O[l >> 6][l & 63];
    __syncthreads();
#pragma unroll
    for (int i = 0; i < 16; ++i) smU.pj.O[n_l][w * 16 + i] = accv[i];
    __syncthreads();
    for (int l = t; l < 64 * 64; l += 256)
      v_t[(b * NPTS2 + n0 + (l >> 6)) * DIM + (l & 63)] = smU.pj.O[l >> 6][l & 63];
  } else if (bid < FB_PQ) {
    // ---------------- proj_q ----------------
    const int vb = bid - FB_PKV;
    const int b  = vb >> 6;
    const int n0 = (vb & 63) * 64;
    for (int l = t; l < CIN * 64; l += 256) {
      int c = l >> 6, i = l & 63;
      smU.pj.X[c][i] = query[(b * CIN + c) * NPTS + n0 + i];
    }
    __syncthreads();
    const int n_l = t & 63;
    const int w   = __builtin_amdgcn_readfirstlane(t >> 6);
    float acc[16];
#pragma unroll
    for (int i = 0; i < 16; ++i) acc[i] = bq[w * 16 + i];
    for (int c = 0; c < CIN; ++c) {
      float xv = smU.pj.X[c][n_l];
#pragma unroll
      for (int i = 0; i < 16; ++i) acc[i] += wq[(w * 16 + i) * CIN + c] * xv;
    }
#pragma unroll
    for (int i = 0; i < 16; ++i) smU.pj.O[n_l][w * 16 + i] = acc[i];
    __syncthreads();
    for (int l = t; l < 64 * 64; l += 256)
      q_t[(b * NPTS + n0 + (l >> 6)) * DIM + (l & 63)] = smU.pj.O[l >> 6][l & 63];
  } else {
    // ---------------- pack_weights ----------------
    int i = (bid - FB_PQ) * 256 + t;
    if (i < 16384) {
      int j = i >> 6;
      float inv = ag[j] / sqrtf(av[j] + EPSF);
      aw1h[i] = (_Float16)(aw1[i] * inv);
    }
    if (i < 32768) {
      int orr = i >> 8, j = i & 255;
      awtP[i] = (_Float16)awt[j * 128 + orr];
    }
    if (i < 4096) pw2h[i] = (_Float16)pw2[i];
    if (i < 256) {
      float inv = ag[i] / sqrtf(av[i] + EPSF);
      ab1f[i] = ab1[i] * inv + (abt2[i] - am[i] * inv);
    }
    if (i < 192) {
      int hc = i / 3;
      float inv = pg[hc] / sqrtf(pv[hc] + EPSF);
      pw1f[i] = pw1[i] * inv;
    }
    if (i < 128) abtX[i] = abt[i >> 1];
    if (i < 64) {
      float inv = pg[i] / sqrtf(pv[i] + EPSF);
      pb1f[i] = pb1[i] * inv + (pbt[i] - pm[i] * inv);
    }
  }
}

// ---------------------------------------------------------------------------
// attn_mfma (R17): 5 waves/SIMD via real register shave.
//  R16 post-mortem: swizzle halved FETCH (36.9->16.6MB) with NO time gain ->
//  attn is stall-bound, not L2/BW-bound (reverted; also WRITE doubled).
//  setprio starved sibling blocks' waves (reverted). The lever left is a 5th
//  wave/SIMD: current 64 VGPR + 64 AGPR = 128/wave caps at 4. Shave: drop
//  the persistent bs[2][4] (32 regs) -- keep hB in R1 for ALL of C/D
//  (single-buffered aL in R0, +3 barriers) and reload B-operands from LDS
//  inside each quarter with a ks-split (16 transient regs). Peak liveness
//  ~accD(32)+transient(32)+addr -> fits 102 = 512/5. launch_bounds(256,5).
//  LDS 27136 x 5 = 135680 <= 163840 -> 5 blocks/CU, 20 waves.
//  Verify: WRITE_SIZE ~27MB (no new spill); >60MB = failed fit, revert.
// LDS map: R0 [0,9216) h1B -> aL (single, quarters sequential);
//          R1 [9216,18432) peL -> hB (persists through C3);
//          lgc [0,17408) (post D3 barrier); VGB [18432,27136) 64x68 f16.
// ---------------------------------------------------------------------------
#define SM_R0    0
#define SM_R1    9216
#define SM_LGC   0
#define SM_VGB   18432

__global__ __launch_bounds__(256, 5) void attn_mfma(
    const float* __restrict__ q_t, const float* __restrict__ k_t,
    const float* __restrict__ v_t, const int* __restrict__ idx,
    const float* __restrict__ pos1, const float* __restrict__ pos2,
    const float* __restrict__ pw1f, const float* __restrict__ pb1f,
    const _Float16* __restrict__ pw2h, const float* __restrict__ pb2,
    const _Float16* __restrict__ aw1h, const float* __restrict__ ab1f,
    const _Float16* __restrict__ awtP, const float* __restrict__ abtX,
    float* __restrict__ agg) {
  __shared__ __align__(16) char smem[27136];
  const int b  = blockIdx.x / BPB;
  const int n0 = (blockIdx.x - b * BPB) * QPB;
  const int t  = threadIdx.x;
  const int lane = t & 63;
  const int w  = t >> 6;        // wave id
  const int r  = lane & 15;     // tile lane index
  const int q4 = lane >> 4;     // quad

  // Per-thread neighbor index (no sj LDS; redundant x4, L1-cached)
  const int colB = t & 63, cgB = t >> 6;
  const int pB = colB / 20, kkB = colB - pB * 20;
  const bool okB = (pB < QPB) && (n0 + pB < NPTS);
  const int nqB = okB ? (n0 + pB) : 0;
  int jB = 0;
  if (okB) jB = idx[(b * NPTS + nqB) * KNN + kkB];

  // Prefetch gather rows; fold q-k immediately (frees 16 f32 regs).
  f32x4 qk4[4], vv4[4];
  {
    const float* qrow = q_t + ((size_t)(b * NPTS  + nqB)) * DIM + cgB * 16;
    const float* krow = k_t + ((size_t)(b * NPTS2 + jB))  * DIM + cgB * 16;
    const float* vrow = v_t + ((size_t)(b * NPTS2 + jB))  * DIM + cgB * 16;
#pragma unroll
    for (int u = 0; u < 4; ++u) {
      f32x4 qv = *(const f32x4*)(qrow + u * 4);
      f32x4 kv = *(const f32x4*)(krow + u * 4);
      qk4[u] = qv - kv;
      vv4[u] = *(const f32x4*)(vrow + u * 4);
    }
  }

  // Phase 1: pos-MLP hidden (BN folded) -> h1B f16 [col][hc] stride 72 (R0)
  {
    float p0 = 0.f, p1 = 0.f, p2 = 0.f;
    if (okB) {
      p0 = pos1[(b * 3 + 0) * NPTS + nqB] - pos2[(b * 3 + 0) * NPTS2 + jB];
      p1 = pos1[(b * 3 + 1) * NPTS + nqB] - pos2[(b * 3 + 1) * NPTS2 + jB];
      p2 = pos1[(b * 3 + 2) * NPTS + nqB] - pos2[(b * 3 + 2) * NPTS2 + jB];
    }
#pragma unroll
    for (int hf = 0; hf < 2; ++hf) {
      h16x8 pk;
#pragma unroll
      for (int ii = 0; ii < 8; ++ii) {
        int hc = cgB * 16 + hf * 8 + ii;
        float v0 = pb1f[hc] + pw1f[hc*3] * p0 + pw1f[hc*3+1] * p1 + pw1f[hc*3+2] * p2;
        v0 = fmaxf(v0, 0.f);
        if (!okB) v0 = 0.f;
        pk[ii] = (_Float16)v0;
      }
      *(h16x8*)(smem + SM_R0 + ((colB * 72 + cgB * 16 + hf * 8) * 2)) = pk;
    }
  }
  __syncthreads();   // bar 1: h1B cross-wave for A

  // Phase A: GEMM0 pe = pw2 @ h1 (+pb2) -> peL f16 [col][o] stride 72 (R1)
  {
    f32x4 acc[4];
#pragma unroll
    for (int nt = 0; nt < 4; ++nt) acc[nt] = (f32x4){0.f, 0.f, 0.f, 0.f};
#pragma unroll
    for (int ks = 0; ks < 2; ++ks) {
      h16x8 a0 = *(const h16x8*)&pw2h[(w * 16 + r) * 64 + ks * 32 + q4 * 8];
#pragma unroll
      for (int nt = 0; nt < 4; ++nt) {
        h16x8 bv = *(h16x8*)(smem + SM_R0 + ((nt * 16 + r) * 72 + ks * 32 + q4 * 8) * 2);
        acc[nt] = __builtin_amdgcn_mfma_f32_16x16x32_f16(a0, bv, acc[nt], 0, 0, 0);
      }
    }
    int o0 = w * 16 + q4 * 4;
    f32x4 pbv = *(const f32x4*)&pb2[o0];
#pragma unroll
    for (int nt = 0; nt < 4; ++nt) {
      f32x4 vv = acc[nt] + pbv;
      h16x4 pk = {(_Float16)vv[0], (_Float16)vv[1], (_Float16)vv[2], (_Float16)vv[3]};
      *(h16x4*)(smem + SM_R1 + ((nt * 16 + r) * 72 + o0) * 2) = pk;
    }
  }
  // NO barrier: wave w wrote peL ch [16w,16w+16) for all cols; B's thread
  // (colB, cgB=w) reads only that range. Per-wave LDS is in-order.

  // Phase B: h = (q-k)+pe IN PLACE over peL (R1); vg -> vgB stride 68.
  {
    h16x8 pe8[2];
#pragma unroll
    for (int hf = 0; hf < 2; ++hf)
      pe8[hf] = *(h16x8*)(smem + SM_R1 + (colB * 72 + cgB * 16 + hf * 8) * 2);
    h16x8 hp8[2];
#pragma unroll
    for (int u = 0; u < 4; ++u) {
      int hf = u >> 1, e0 = (u & 1) * 4;
      f32x4 pe = {(float)pe8[hf][e0],     (float)pe8[hf][e0 + 1],
                  (float)pe8[hf][e0 + 2], (float)pe8[hf][e0 + 3]};
      f32x4 hv = qk4[u] + pe;
      f32x4 gv = vv4[u] + pe;
      if (!okB) { hv = (f32x4){0.f,0.f,0.f,0.f}; gv = hv; }
      hp8[hf][e0]     = (_Float16)hv[0];
      hp8[hf][e0 + 1] = (_Float16)hv[1];
      hp8[hf][e0 + 2] = (_Float16)hv[2];
      hp8[hf][e0 + 3] = (_Float16)hv[3];
      h16x4 gp = {(_Float16)gv[0], (_Float16)gv[1], (_Float16)gv[2], (_Float16)gv[3]};
      *(h16x4*)(smem + SM_VGB + (colB * 68 + cgB * 16 + u * 4) * 2) = gp;
    }
#pragma unroll
    for (int hf = 0; hf < 2; ++hf)
      *(h16x8*)(smem + SM_R1 + (colB * 72 + cgB * 16 + hf * 8) * 2) = hp8[hf];
  }
  __syncthreads();   // bar 2: hB (R1) cross-wave for C; h1B (R0) dead -> aL

  // Phases C+D over four j-quarters; single aL buffer in R0, hB persists in
  // R1 through C3. No persistent bs registers: C reloads B-operands from hB
  // per ks (16 transient regs) -- the -32-reg shave that buys wave 5.
  f32x4 accD[2][4];
#pragma unroll
  for (int h = 0; h < 2; ++h)
#pragma unroll
    for (int nt = 0; nt < 4; ++nt) accD[h][nt] = (f32x4){0.f, 0.f, 0.f, 0.f};

#define C_QUARTER(quar)                                                        \
  {                                                                            \
    int mt = (quar) * 4 + w;                                                   \
    f32x4 acc[4];                                                              \
    _Pragma("unroll")                                                          \
    for (int nt = 0; nt < 4; ++nt) acc[nt] = (f32x4){0.f, 0.f, 0.f, 0.f};      \
    _Pragma("unroll")                                                          \
    for (int ks = 0; ks < 2; ++ks) {                                           \
      h16x8 af = *(const h16x8*)&aw1h[(mt * 16 + r) * 64 + ks * 32 + q4 * 8];  \
      h16x8 bsv[4];                                                            \
      _Pragma("unroll")                                                        \
      for (int nt = 0; nt < 4; ++nt)                                           \
        bsv[nt] = *(h16x8*)(smem + SM_R1 + ((nt * 16 + r) * 72 + ks * 32 + q4 * 8) * 2); \
      _Pragma("unroll")                                                        \
      for (int nt = 0; nt < 4; ++nt)                                           \
        acc[nt] = __builtin_amdgcn_mfma_f32_16x16x32_f16(af, bsv[nt], acc[nt], 0, 0, 0); \
    }                                                                          \
    int j0  = mt * 16 + q4 * 4;                                                \
    int jq0 = j0 - (quar) * 64;                                                \
    f32x4 b1 = *(const f32x4*)&ab1f[j0];                                       \
    _Pragma("unroll")                                                          \
    for (int nt = 0; nt < 4; ++nt) {                                           \
      int col = nt * 16 + r;                                                   \
      float v0 = fmaxf(acc[nt][0] + b1[0], 0.f);                               \
      float v1 = fmaxf(acc[nt][1] + b1[1], 0.f);                               \
      float v2 = fmaxf(acc[nt][2] + b1[2], 0.f);                               \
      float v3 = fmaxf(acc[nt][3] + b1[3], 0.f);                               \
      h16x4 pk = {(_Float16)v0, (_Float16)v1, (_Float16)v2, (_Float16)v3};     \
      *(h16x4*)(smem + SM_R0 + (col * 72 + jq0) * 2) = pk;                     \
    }                                                                          \
  }

#define D_QUARTER(quar)                                                        \
  {                                                                            \
    _Pragma("unroll")                                                          \
    for (int ks2 = 0; ks2 < 2; ++ks2) {                                        \
      h16x8 bsv[4];                                                            \
      _Pragma("unroll")                                                        \
      for (int nt = 0; nt < 4; ++nt)                                           \
        bsv[nt] = *(h16x8*)(smem + SM_R0 + ((nt * 16 + r) * 72 + ks2 * 32 + q4 * 8) * 2); \
      int ksg = (quar) * 2 + ks2;                                              \
      _Pragma("unroll")                                                        \
      for (int h = 0; h < 2; ++h) {                                            \
        int mt2 = w * 2 + h;                                                   \
        h16x8 af = *(const h16x8*)&awtP[(mt2 * 16 + r) * 256 + ksg * 32 + q4 * 8]; \
        _Pragma("unroll")                                                      \
        for (int nt = 0; nt < 4; ++nt)                                         \
          accD[h][nt] = __builtin_amdgcn_mfma_f32_16x16x32_f16(af, bsv[nt], accD[h][nt], 0, 0, 0); \
      }                                                                        \
    }                                                                          \
  }

  C_QUARTER(0)
  __syncthreads();   // C0 visible for D0
  D_QUARTER(0)
  __syncthreads();   // D0 reads done before C1 overwrites aL
  C_QUARTER(1)
  __syncthreads();
  D_QUARTER(1)
  __syncthreads();
  C_QUARTER(2)
  __syncthreads();
  D_QUARTER(2)
  __syncthreads();
  C_QUARTER(3)
  __syncthreads();
  D_QUARTER(3)
  __syncthreads();   // D3's R0 reads complete before lgc writes R0+R1

  // lgc write: full 64x136 f16 over R0+R1 (hB dead after C3; aL dead)
  {
#pragma unroll
    for (int h = 0; h < 2; ++h) {
      int orr0 = (w * 2 + h) * 16 + q4 * 4;
      f32x4 ab = *(const f32x4*)&abtX[orr0];
#pragma unroll
      for (int nt = 0; nt < 4; ++nt) {
        int col = nt * 16 + r;
        if (col < QPB * KNN) {
          f32x4 vv = accD[h][nt] + ab;
          h16x4 pk = {(_Float16)vv[0], (_Float16)vv[1], (_Float16)vv[2], (_Float16)vv[3]};
          *(h16x4*)(smem + SM_LGC + (col * 136 + orr0) * 2) = pk;
        }
      }
    }
  }
  __syncthreads();   // lgc cross-wave for E

  // Phase E: lane li owns output channel o=li for both upsample rows.
  if (t < 64 * QPB) {
    int li = t & 63, p = t >> 6;
    if (n0 + p < NPTS) {
      h16x2 Lp[KNN];
      float G[KNN];
#pragma unroll
      for (int kk = 0; kk < KNN; ++kk) {
        Lp[kk] = *(h16x2*)(smem + SM_LGC + ((p * 20 + kk) * 136 + li * 2) * 2);
        G[kk]  = (float)*(_Float16*)(smem + SM_VGB + ((p * 20 + kk) * 68 + li) * 2);
      }
#pragma unroll
      for (int half = 0; half < 2; ++half) {
        float mx = (float)Lp[0][half];
#pragma unroll
        for (int kk = 1; kk < KNN; ++kk) mx = fmaxf(mx, (float)Lp[kk][half]);
        float s = 0.f, a = 0.f;
#pragma unroll
        for (int kk = 0; kk < KNN; ++kk) {
          float e = __expf((float)Lp[kk][half] - mx);
          s += e;
          a += e * G[kk];
        }
        float rs = 1.0f / s;
        agg[(((size_t)(b * NPTS + n0 + p)) * UPF + half) * DIM + li] = a * rs;
      }
    }
  }
#undef C_QUARTER
#undef D_QUARTER
}

// ---------------------------------------------------------------------------
// out_proj (unchanged)
// ---------------------------------------------------------------------------
__global__ __launch_bounds__(256) void out_proj(const float* __restrict__ agg,
    const float* __restrict__ we, const float* __restrict__ be,
    const float* __restrict__ query, float* __restrict__ out) {
  __shared__ float A[64][65];
  const int b  = blockIdx.x >> 7;
  const int m0 = (blockIdx.x & 127) * 64;
  const int t  = threadIdx.x;
  for (int l = t; l < 64 * 64; l += 256) {
    int row = l >> 6, c = l & 63;
    A[row][c] = agg[(b * MOUT + m0 + row) * DIM + c];
  }
  __syncthreads();
  const int m_l = t & 63;
  const int w   = __builtin_amdgcn_readfirstlane(t >> 6);
  float acc[32];
#pragma unroll
  for (int i = 0; i < 32; ++i) acc[i] = 0.f;
  for (int c = 0; c < DIM; ++c) {
    float a = A[m_l][c];
#pragma unroll
    for (int i = 0; i < 32; ++i) acc[i] += we[(w * 32 + i) * DIM + c] * a;
  }
  const int m = m0 + m_l;
#pragma unroll
  for (int i = 0; i < 32; ++i) {
    int o = w * 32 + i;
    out[(b * CIN + o) * MOUT + m] = acc[i] + be[o] + query[(b * CIN + o) * NPTS + (m >> 1)];
  }
}

// ---------------------------------------------------------------------------
extern "C" void kernel_launch(void* const* d_in, const int* in_sizes, int n_in,
                              void* d_out, int out_size, void* d_ws, size_t ws_size,
                              hipStream_t stream) {
  (void)in_sizes; (void)n_in; (void)out_size; (void)ws_size;
  const float* pos1     = (const float*)d_in[0];
  const float* query    = (const float*)d_in[1];
  const float* pos2     = (const float*)d_in[2];
  const float* key_feat = (const float*)d_in[3];
  const float* wq  = (const float*)d_in[4];
  const float* bq  = (const float*)d_in[5];
  const float* wk  = (const float*)d_in[6];
  const float* bk  = (const float*)d_in[7];
  const float* wv  = (const float*)d_in[8];
  const float* bv  = (const float*)d_in[9];
  const float* pw1 = (const float*)d_in[10];
  const float* pb1 = (const float*)d_in[11];
  const float* pg  = (const float*)d_in[12];
  const float* pbt = (const float*)d_in[13];
  const float* pm  = (const float*)d_in[14];
  const float* pv  = (const float*)d_in[15];
  const float* pw2 = (const float*)d_in[16];
  const float* pb2 = (const float*)d_in[17];
  const float* aw1 = (const float*)d_in[18];
  const float* ab1 = (const float*)d_in[19];
  const float* ag  = (const float*)d_in[20];
  const float* abt2= (const float*)d_in[21];
  const float* am  = (const float*)d_in[22];
  const float* av  = (const float*)d_in[23];
  const float* awt = (const float*)d_in[24];
  const float* abt = (const float*)d_in[25];
  const float* we  = (const float*)d_in[26];
  const float* be  = (const float*)d_in[27];

  float* ws   = (float*)d_ws;
  float* q_t  = ws;
  float* k_t  = q_t + BATCH * NPTS * DIM;
  float* v_t  = k_t + BATCH * NPTS2 * DIM;
  float* aggb = v_t + BATCH * NPTS2 * DIM;
  int*   idxb = (int*)(aggb + BATCH * MOUT * DIM);
  _Float16* aw1h = (_Float16*)(idxb + BATCH * NPTS * KNN);
  _Float16* awtP = aw1h + HATT * DIM;
  _Float16* pw2h = awtP + 128 * HATT;
  float* abtX    = (float*)(pw2h + DIM * HPOS);
  float* ab1f    = abtX + 128;
  float* pw1f    = ab1f + HATT;
  float* pb1f    = pw1f + HPOS * 3;

  front<<<FB_PACK, 256, 0, stream>>>(
      pos1, pos2, idxb,
      key_feat, wk, bk, wv, bv, k_t, v_t,
      query, wq, bq, q_t,
      aw1, awt, pw2, ag, av, abt2, am, abt,
      pg, pv, pbt, pm, ab1, pb1, pw1,
      aw1h, awtP, pw2h, abtX, ab1f, pw1f, pb1f);
  attn_mfma<<<BATCH * BPB, 256, 0, stream>>>(q_t, k_t, v_t, idxb, pos1, pos2,
      pw1f, pb1f, pw2h, pb2, aw1h, ab1f, awtP, abtX, aggb);
  out_proj<<<BATCH * (MOUT / 64), 256, 0, stream>>>(aggb, we, be, query, (float*)d_out);
}

// Round 7
// 314.369 us; speedup vs baseline: 1.0357x; 1.0357x over previous
//
#include <hip/hip_runtime.h>
#include <hip/hip_bf16.h>

#define BATCH 4
#define NPTS  4096
#define NPTS2 4096
#define CIN   128
#define DIM   64
#define KNN   20
#define UPF   2
#define HPOS  64
#define HATT  256
#define MOUT  8192
#define EPSF  1e-5f
#define QPB   6            // queries per attn block (R18: doubled)
#define BPB   683          // ceil(4096/6) attn blocks per batch

// front kernel block ranges
#define FB_KNN   1024
#define FB_PKV   (FB_KNN + 256)
#define FB_PQ    (FB_PKV + 256)
#define FB_PACK  (FB_PQ + 128)

typedef _Float16 h16x8 __attribute__((ext_vector_type(8)));
typedef _Float16 h16x4 __attribute__((ext_vector_type(4)));
typedef _Float16 h16x2 __attribute__((ext_vector_type(2)));
typedef float    f32x4 __attribute__((ext_vector_type(4)));

__device__ inline float rdlane(float v, int src) {
  return __int_as_float(__builtin_amdgcn_readlane(__float_as_int(v), src));
}

// Bit-exact distance: explicit fma DAG -> identical value in every use site.
__device__ __forceinline__ float distf(float qn, float m2x, float m2y, float m2z,
                                       float x, float y, float z) {
  float s = __fmaf_rn(x, x, qn);
  s = __fmaf_rn(y, y, s);
  s = __fmaf_rn(z, z, s);
  s = __fmaf_rn(m2x, x, s);
  s = __fmaf_rn(m2y, y, s);
  s = __fmaf_rn(m2z, z, s);
  return s;
}

// ---------------------------------------------------------------------------
// front (unchanged from R15): fused {knn v5, proj_kv, proj_q, pack_weights}.
// ---------------------------------------------------------------------------
__global__ __launch_bounds__(256) void front(
    // knn
    const float* __restrict__ pos1, const float* __restrict__ pos2,
    int* __restrict__ idxout,
    // proj_kv
    const float* __restrict__ key_feat,
    const float* __restrict__ wk, const float* __restrict__ bk,
    const float* __restrict__ wv, const float* __restrict__ bv,
    float* __restrict__ k_t, float* __restrict__ v_t,
    // proj_q
    const float* __restrict__ query,
    const float* __restrict__ wq, const float* __restrict__ bq,
    float* __restrict__ q_t,
    // pack_weights
    const float* __restrict__ aw1, const float* __restrict__ awt,
    const float* __restrict__ pw2,
    const float* __restrict__ ag,  const float* __restrict__ av,
    const float* __restrict__ abt2, const float* __restrict__ am,
    const float* __restrict__ abt,
    const float* __restrict__ pg,  const float* __restrict__ pv,
    const float* __restrict__ pbt, const float* __restrict__ pm,
    const float* __restrict__ ab1, const float* __restrict__ pb1,
    const float* __restrict__ pw1,
    _Float16* __restrict__ aw1h, _Float16* __restrict__ awtP,
    _Float16* __restrict__ pw2h, float* __restrict__ abtX,
    float* __restrict__ ab1f, float* __restrict__ pw1f,
    float* __restrict__ pb1f) {
  __shared__ union {
    struct { float X[CIN][64]; float O[64][65]; } pj;
    struct { int cnt[16]; float dbuf[16][64]; int jbuf[16][64]; } kn;
  } smU;
  const int bid = blockIdx.x;
  const int t   = threadIdx.x;

  if (bid < FB_KNN) {
    // ---------------- knn v5 ----------------
    const int lane = t & 63;
    const int wv   = t >> 6;
    const int b    = bid >> 8;           // 256 blocks per batch
    const int nb   = (bid & 255) * 16;   // 16 queries per block
    const float* p2x = pos2 + (b * 3 + 0) * NPTS2;
    const float* p2y = pos2 + (b * 3 + 1) * NPTS2;
    const float* p2z = pos2 + (b * 3 + 2) * NPTS2;

    float qn[4], m2x[4], m2y[4], m2z[4];
#pragma unroll
    for (int qi = 0; qi < 4; ++qi) {
      int n = nb + wv * 4 + qi;
      float qx = pos1[(b * 3 + 0) * NPTS + n];
      float qy = pos1[(b * 3 + 1) * NPTS + n];
      float qz = pos1[(b * 3 + 2) * NPTS + n];
      qn[qi]  = qx * qx + qy * qy + qz * qz;
      m2x[qi] = -2.0f * qx; m2y[qi] = -2.0f * qy; m2z[qi] = -2.0f * qz;
    }

    float mymin[4] = {3.402823466e38f, 3.402823466e38f,
                      3.402823466e38f, 3.402823466e38f};
    f32x4 cx[4], cy[4], cz[4];
#pragma unroll 1
    for (int c = 0; c < 4; ++c) {
      int base = c * 1024 + lane * 4;
#pragma unroll
      for (int g = 0; g < 4; ++g) {
        cx[g] = *(const f32x4*)(p2x + base + g * 256);
        cy[g] = *(const f32x4*)(p2y + base + g * 256);
        cz[g] = *(const f32x4*)(p2z + base + g * 256);
      }
#pragma unroll
      for (int qi = 0; qi < 4; ++qi)
#pragma unroll
        for (int g = 0; g < 4; ++g)
#pragma unroll
          for (int e = 0; e < 4; ++e) {
            float d = distf(qn[qi], m2x[qi], m2y[qi], m2z[qi],
                            cx[g][e], cy[g][e], cz[g][e]);
            mymin[qi] = fminf(mymin[qi], d);
          }
    }

    float T0[4];
#pragma unroll
    for (int qi = 0; qi < 4; ++qi) {
      float v = mymin[qi];
#pragma unroll
      for (int k = 2; k <= 64; k <<= 1)
#pragma unroll
        for (int jj = k >> 1; jj >= 1; jj >>= 1) {
          float o = __shfl_xor(v, jj);
          bool up = ((lane & k) == 0);
          bool keepmin = (((lane & jj) == 0) == up);
          v = keepmin ? fminf(v, o) : fmaxf(v, o);
        }
      T0[qi] = rdlane(v, 19);
    }

    if (lane < 4) smU.kn.cnt[wv * 4 + lane] = 0;
    // per-wave private buffers; per-wave LDS in-order -> no barrier

#pragma unroll 1
    for (int c = 0; c < 4; ++c) {
      int base = c * 1024 + lane * 4;
#pragma unroll
      for (int g = 0; g < 4; ++g) {
        cx[g] = *(const f32x4*)(p2x + base + g * 256);
        cy[g] = *(const f32x4*)(p2y + base + g * 256);
        cz[g] = *(const f32x4*)(p2z + base + g * 256);
      }
#pragma unroll
      for (int qi = 0; qi < 4; ++qi) {
        const int qq = wv * 4 + qi;
#pragma unroll
        for (int g = 0; g < 4; ++g)
#pragma unroll
          for (int e = 0; e < 4; ++e) {
            float d = distf(qn[qi], m2x[qi], m2y[qi], m2z[qi],
                            cx[g][e], cy[g][e], cz[g][e]);
            if (d <= T0[qi]) {
              int slot = atomicAdd(&smU.kn.cnt[qq], 1);
              if (slot < 64) { smU.kn.dbuf[qq][slot] = d; smU.kn.jbuf[qq][slot] = base + g * 256 + e; }
            }
          }
      }
    }

#pragma unroll 1
    for (int qi = 0; qi < 4; ++qi) {
      const int qq = wv * 4 + qi;
      const int n  = nb + qq;
      const int cnt = smU.kn.cnt[qq];
      if (cnt <= 64) {
        float dk = (lane < cnt) ? smU.kn.dbuf[qq][lane] : 3.402823466e38f;
        int   jk = (lane < cnt) ? smU.kn.jbuf[qq][lane] : 0x7fffffff;
#pragma unroll
        for (int k = 2; k <= 64; k <<= 1) {
#pragma unroll
          for (int jj = k >> 1; jj >= 1; jj >>= 1) {
            float od = __shfl_xor(dk, jj);
            int   oj = __shfl_xor(jk, jj);
            bool mineSm = (dk < od) || (dk == od && jk < oj);
            bool up = ((lane & k) == 0);
            bool keepmin = (((lane & jj) == 0) == up);
            bool takeOther = (keepmin != mineSm);
            dk = takeOther ? od : dk;
            jk = takeOther ? oj : jk;
          }
        }
        if (lane < KNN) idxout[(b * NPTS + n) * KNN + lane] = jk;
      } else {
        float dl = 3.402823466e38f;
        int   il = 0;
        for (int j0 = 0; j0 < NPTS2; j0 += 64) {
          int j = j0 + lane;
          float d = distf(qn[qi], m2x[qi], m2y[qi], m2z[qi], p2x[j], p2y[j], p2z[j]);
          float T = rdlane(dl, 19);
          unsigned long long m = __ballot(d < T);
          while (m) {
            int src = __ffsll(m) - 1;
            m &= m - 1;
            float dd = rdlane(d, src);
            float T2 = rdlane(dl, 19);
            if (dd < T2) {
              int jj2 = j0 + src;
              float pd = __shfl_up(dl, 1);
              int   pi = __shfl_up(il, 1);
              if (dl > dd) {
                if (lane == 0 || pd <= dd) { dl = dd; il = jj2; }
                else                       { dl = pd; il = pi; }
              }
            }
          }
        }
        if (lane < KNN) idxout[(b * NPTS + n) * KNN + lane] = il;
      }
    }
  } else if (bid < FB_PKV) {
    // ---------------- proj_kv ----------------
    const int vb = bid - FB_KNN;
    const int b  = vb >> 6;
    const int n0 = (vb & 63) * 64;
    for (int l = t; l < CIN * 64; l += 256) {
      int c = l >> 6, i = l & 63;
      smU.pj.X[c][i] = key_feat[(b * CIN + c) * NPTS2 + n0 + i];
    }
    __syncthreads();
    const int n_l = t & 63;
    const int w   = __builtin_amdgcn_readfirstlane(t >> 6);
    float acck[16], accv[16];
#pragma unroll
    for (int i = 0; i < 16; ++i) { acck[i] = bk[w * 16 + i]; accv[i] = bv[w * 16 + i]; }
    for (int c = 0; c < CIN; ++c) {
      float xv = smU.pj.X[c][n_l];
#pragma unroll
      for (int i = 0; i < 16; ++i) {
        acck[i] += wk[(w * 16 + i) * CIN + c] * xv;
        accv[i] += wv[(w * 16 + i) * CIN + c] * xv;
      }
    }
#pragma unroll
    for (int i = 0; i < 16; ++i) smU.pj.O[n_l][w * 16 + i] = acck[i];
    __syncthreads();
    for (int l = t; l < 64 * 64; l += 256)
      k_t[(b * NPTS2 + n0 + (l >> 6)) * DIM + (l & 63)] = smU.pj.O[l >> 6][l & 63];
    __syncthreads();
#pragma unroll
    for (int i = 0; i < 16; ++i) smU.pj.O[n_l][w * 16 + i] = accv[i];
    __syncthreads();
    for (int l = t; l < 64 * 64; l += 256)
      v_t[(b * NPTS2 + n0 + (l >> 6)) * DIM + (l & 63)] = smU.pj.O[l >> 6][l & 63];
  } else if (bid < FB_PQ) {
    // ---------------- proj_q ----------------
    const int vb = bid - FB_PKV;
    const int b  = vb >> 6;
    const int n0 = (vb & 63) * 64;
    for (int l = t; l < CIN * 64; l += 256) {
      int c = l >> 6, i = l & 63;
      smU.pj.X[c][i] = query[(b * CIN + c) * NPTS + n0 + i];
    }
    __syncthreads();
    const int n_l = t & 63;
    const int w   = __builtin_amdgcn_readfirstlane(t >> 6);
    float acc[16];
#pragma unroll
    for (int i = 0; i < 16; ++i) acc[i] = bq[w * 16 + i];
    for (int c = 0; c < CIN; ++c) {
      float xv = smU.pj.X[c][n_l];
#pragma unroll
      for (int i = 0; i < 16; ++i) acc[i] += wq[(w * 16 + i) * CIN + c] * xv;
    }
#pragma unroll
    for (int i = 0; i < 16; ++i) smU.pj.O[n_l][w * 16 + i] = acc[i];
    __syncthreads();
    for (int l = t; l < 64 * 64; l += 256)
      q_t[(b * NPTS + n0 + (l >> 6)) * DIM + (l & 63)] = smU.pj.O[l >> 6][l & 63];
  } else {
    // ---------------- pack_weights ----------------
    int i = (bid - FB_PQ) * 256 + t;
    if (i < 16384) {
      int j = i >> 6;
      float inv = ag[j] / sqrtf(av[j] + EPSF);
      aw1h[i] = (_Float16)(aw1[i] * inv);
    }
    if (i < 32768) {
      int orr = i >> 8, j = i & 255;
      awtP[i] = (_Float16)awt[j * 128 + orr];
    }
    if (i < 4096) pw2h[i] = (_Float16)pw2[i];
    if (i < 256) {
      float inv = ag[i] / sqrtf(av[i] + EPSF);
      ab1f[i] = ab1[i] * inv + (abt2[i] - am[i] * inv);
    }
    if (i < 192) {
      int hc = i / 3;
      float inv = pg[hc] / sqrtf(pv[hc] + EPSF);
      pw1f[i] = pw1[i] * inv;
    }
    if (i < 128) abtX[i] = abt[i >> 1];
    if (i < 64) {
      float inv = pg[i] / sqrtf(pv[i] + EPSF);
      pb1f[i] = pb1[i] * inv + (pbt[i] - pm[i] * inv);
    }
  }
}

// ---------------------------------------------------------------------------
// attn_mfma (R18): QPB 3->6 structural doubling.
//  R13-R17 evidence: attn pinned at ~130us under occupancy +23%, FETCH -55%,
//  WRITE +-6x, barriers 4->8, setprio, swizzle -> NOT resource-bound; the
//  floor is the phase structure (tiny per-phase work, phase-locked convoys).
//  R18 doubles the tile: 128 logit cols (120 real), 2732 blocks, nt-loop 8:
//  each LDS-read batch feeds 2x the MFMAs, half the barrier convoys per
//  unit work. LDS 54272 B -> 3 blocks/CU (occupancy drop is proven-free);
//  (256,3) caps regs at 170, demand ~110-130 -> no spill expected.
//  Verify: WRITE_SIZE ~8-10MB (>30MB = spill = failed).
// LDS map: R0 [0,18432) h1B -> aL (single buffer, quarters sequential);
//          R1 [18432,36864) peL -> hB (persists through C3);
//          lgc [0,34816) (post-D3); VGB [36864,54272) 128x68 f16.
// ---------------------------------------------------------------------------
#define SM_R0    0
#define SM_R1    18432
#define SM_LGC   0
#define SM_VGB   36864

__global__ __launch_bounds__(256, 3) void attn_mfma(
    const float* __restrict__ q_t, const float* __restrict__ k_t,
    const float* __restrict__ v_t, const int* __restrict__ idx,
    const float* __restrict__ pos1, const float* __restrict__ pos2,
    const float* __restrict__ pw1f, const float* __restrict__ pb1f,
    const _Float16* __restrict__ pw2h, const float* __restrict__ pb2,
    const _Float16* __restrict__ aw1h, const float* __restrict__ ab1f,
    const _Float16* __restrict__ awtP, const float* __restrict__ abtX,
    float* __restrict__ agg) {
  __shared__ __align__(16) char smem[54272];
  const int b  = blockIdx.x / BPB;
  const int n0 = (blockIdx.x - b * BPB) * QPB;
  const int t  = threadIdx.x;
  const int lane = t & 63;
  const int w  = t >> 6;        // wave id
  const int r  = lane & 15;     // tile lane index
  const int q4 = lane >> 4;     // quad
  const int c0 = t & 63;        // first col; second col = c0 + 64
  const int cgB = w;            // ch-group

  // Neighbor indices for both col-halves (L1-cached idx reads)
  int  jBh[2]; bool okh[2]; int nqh[2];
#pragma unroll
  for (int hl = 0; hl < 2; ++hl) {
    int colB = c0 + hl * 64;
    int pB = colB / 20;
    okh[hl] = (pB < QPB) && (n0 + pB < NPTS);
    nqh[hl] = okh[hl] ? (n0 + pB) : 0;
    jBh[hl] = okh[hl] ? idx[(b * NPTS + nqh[hl]) * KNN + (colB - pB * 20)] : 0;
  }

  // Prefetch half-0 q/k/v (hidden under Phase 1 + A); q-k folded at load.
  f32x4 qk4[4], vv4[4];
  {
    const float* qrow = q_t + ((size_t)(b * NPTS  + nqh[0])) * DIM + cgB * 16;
    const float* krow = k_t + ((size_t)(b * NPTS2 + jBh[0])) * DIM + cgB * 16;
    const float* vrow = v_t + ((size_t)(b * NPTS2 + jBh[0])) * DIM + cgB * 16;
#pragma unroll
    for (int u = 0; u < 4; ++u) {
      f32x4 qv = *(const f32x4*)(qrow + u * 4);
      f32x4 kv = *(const f32x4*)(krow + u * 4);
      qk4[u] = qv - kv;
      vv4[u] = *(const f32x4*)(vrow + u * 4);
    }
  }

  // Phase 1: pos-MLP hidden -> h1B f16 [col][hc] stride 72 (R0), both halves
#pragma unroll
  for (int hl = 0; hl < 2; ++hl) {
    int colB = c0 + hl * 64;
    float p0 = 0.f, p1 = 0.f, p2 = 0.f;
    if (okh[hl]) {
      p0 = pos1[(b * 3 + 0) * NPTS + nqh[hl]] - pos2[(b * 3 + 0) * NPTS2 + jBh[hl]];
      p1 = pos1[(b * 3 + 1) * NPTS + nqh[hl]] - pos2[(b * 3 + 1) * NPTS2 + jBh[hl]];
      p2 = pos1[(b * 3 + 2) * NPTS + nqh[hl]] - pos2[(b * 3 + 2) * NPTS2 + jBh[hl]];
    }
#pragma unroll
    for (int hf = 0; hf < 2; ++hf) {
      h16x8 pk;
#pragma unroll
      for (int ii = 0; ii < 8; ++ii) {
        int hc = cgB * 16 + hf * 8 + ii;
        float v0 = pb1f[hc] + pw1f[hc*3] * p0 + pw1f[hc*3+1] * p1 + pw1f[hc*3+2] * p2;
        v0 = fmaxf(v0, 0.f);
        if (!okh[hl]) v0 = 0.f;
        pk[ii] = (_Float16)v0;
      }
      *(h16x8*)(smem + SM_R0 + ((colB * 72 + cgB * 16 + hf * 8) * 2)) = pk;
    }
  }
  __syncthreads();   // bar 1: h1B cross-wave for A

  // Phase A: GEMM0 pe = pw2 @ h1 (+pb2) -> peL f16 [col][o] stride 72 (R1)
  {
    f32x4 acc[8];
#pragma unroll
    for (int nt = 0; nt < 8; ++nt) acc[nt] = (f32x4){0.f, 0.f, 0.f, 0.f};
#pragma unroll
    for (int ks = 0; ks < 2; ++ks) {
      h16x8 a0 = *(const h16x8*)&pw2h[(w * 16 + r) * 64 + ks * 32 + q4 * 8];
#pragma unroll
      for (int nt = 0; nt < 8; ++nt) {
        h16x8 bv = *(h16x8*)(smem + SM_R0 + ((nt * 16 + r) * 72 + ks * 32 + q4 * 8) * 2);
        acc[nt] = __builtin_amdgcn_mfma_f32_16x16x32_f16(a0, bv, acc[nt], 0, 0, 0);
      }
    }
    int o0 = w * 16 + q4 * 4;
    f32x4 pbv = *(const f32x4*)&pb2[o0];
#pragma unroll
    for (int nt = 0; nt < 8; ++nt) {
      f32x4 vv = acc[nt] + pbv;
      h16x4 pk = {(_Float16)vv[0], (_Float16)vv[1], (_Float16)vv[2], (_Float16)vv[3]};
      *(h16x4*)(smem + SM_R1 + ((nt * 16 + r) * 72 + o0) * 2) = pk;
    }
  }
  // NO barrier: wave w wrote peL ch [16w,16w+16) for ALL 128 cols; B's thread
  // (cols {c0, c0+64}, cgB=w) reads only that range. Per-wave LDS in-order.

  // Phase B: h = (q-k)+pe IN PLACE over peL (R1); vg -> vgB stride 68.
  // unroll 1: process halves sequentially to bound register pressure.
#pragma unroll 1
  for (int hl = 0; hl < 2; ++hl) {
    int colB = c0 + hl * 64;
    if (hl == 1) {
      const float* qrow = q_t + ((size_t)(b * NPTS  + nqh[1])) * DIM + cgB * 16;
      const float* krow = k_t + ((size_t)(b * NPTS2 + jBh[1])) * DIM + cgB * 16;
      const float* vrow = v_t + ((size_t)(b * NPTS2 + jBh[1])) * DIM + cgB * 16;
#pragma unroll
      for (int u = 0; u < 4; ++u) {
        f32x4 qv = *(const f32x4*)(qrow + u * 4);
        f32x4 kv = *(const f32x4*)(krow + u * 4);
        qk4[u] = qv - kv;
        vv4[u] = *(const f32x4*)(vrow + u * 4);
      }
    }
    h16x8 pe8[2];
#pragma unroll
    for (int hf = 0; hf < 2; ++hf)
      pe8[hf] = *(h16x8*)(smem + SM_R1 + (colB * 72 + cgB * 16 + hf * 8) * 2);
    h16x8 hp8[2];
#pragma unroll
    for (int u = 0; u < 4; ++u) {
      int hf = u >> 1, e0 = (u & 1) * 4;
      f32x4 pe = {(float)pe8[hf][e0],     (float)pe8[hf][e0 + 1],
                  (float)pe8[hf][e0 + 2], (float)pe8[hf][e0 + 3]};
      f32x4 hv = qk4[u] + pe;
      f32x4 gv = vv4[u] + pe;
      if (!okh[hl]) { hv = (f32x4){0.f,0.f,0.f,0.f}; gv = hv; }
      hp8[hf][e0]     = (_Float16)hv[0];
      hp8[hf][e0 + 1] = (_Float16)hv[1];
      hp8[hf][e0 + 2] = (_Float16)hv[2];
      hp8[hf][e0 + 3] = (_Float16)hv[3];
      h16x4 gp = {(_Float16)gv[0], (_Float16)gv[1], (_Float16)gv[2], (_Float16)gv[3]};
      *(h16x4*)(smem + SM_VGB + (colB * 68 + cgB * 16 + u * 4) * 2) = gp;
    }
#pragma unroll
    for (int hf = 0; hf < 2; ++hf)
      *(h16x8*)(smem + SM_R1 + (colB * 72 + cgB * 16 + hf * 8) * 2) = hp8[hf];
  }
  __syncthreads();   // bar 2: hB (R1) cross-wave for C; h1B (R0) dead -> aL

  // Phases C+D over four j-quarters; single aL buffer in R0, hB persists in
  // R1 through C3; B-operands reloaded from LDS per ks (transient regs).
  f32x4 accD[2][8];
#pragma unroll
  for (int h = 0; h < 2; ++h)
#pragma unroll
    for (int nt = 0; nt < 8; ++nt) accD[h][nt] = (f32x4){0.f, 0.f, 0.f, 0.f};

#define C_QUARTER(quar)                                                        \
  {                                                                            \
    int mt = (quar) * 4 + w;                                                   \
    f32x4 acc[8];                                                              \
    _Pragma("unroll")                                                          \
    for (int nt = 0; nt < 8; ++nt) acc[nt] = (f32x4){0.f, 0.f, 0.f, 0.f};      \
    _Pragma("unroll")                                                          \
    for (int ks = 0; ks < 2; ++ks) {                                           \
      h16x8 af = *(const h16x8*)&aw1h[(mt * 16 + r) * 64 + ks * 32 + q4 * 8];  \
      h16x8 bsv[8];                                                            \
      _Pragma("unroll")                                                        \
      for (int nt = 0; nt < 8; ++nt)                                           \
        bsv[nt] = *(h16x8*)(smem + SM_R1 + ((nt * 16 + r) * 72 + ks * 32 + q4 * 8) * 2); \
      _Pragma("unroll")                                                        \
      for (int nt = 0; nt < 8; ++nt)                                           \
        acc[nt] = __builtin_amdgcn_mfma_f32_16x16x32_f16(af, bsv[nt], acc[nt], 0, 0, 0); \
    }                                                                          \
    int j0  = mt * 16 + q4 * 4;                                                \
    int jq0 = j0 - (quar) * 64;                                                \
    f32x4 b1 = *(const f32x4*)&ab1f[j0];                                       \
    _Pragma("unroll")                                                          \
    for (int nt = 0; nt < 8; ++nt) {                                           \
      int col = nt * 16 + r;                                                   \
      float v0 = fmaxf(acc[nt][0] + b1[0], 0.f);                               \
      float v1 = fmaxf(acc[nt][1] + b1[1], 0.f);                               \
      float v2 = fmaxf(acc[nt][2] + b1[2], 0.f);                               \
      float v3 = fmaxf(acc[nt][3] + b1[3], 0.f);                               \
      h16x4 pk = {(_Float16)v0, (_Float16)v1, (_Float16)v2, (_Float16)v3};     \
      *(h16x4*)(smem + SM_R0 + (col * 72 + jq0) * 2) = pk;                     \
    }                                                                          \
  }

#define D_QUARTER(quar)                                                        \
  {                                                                            \
    _Pragma("unroll")                                                          \
    for (int ks2 = 0; ks2 < 2; ++ks2) {                                        \
      h16x8 bsv[8];                                                            \
      _Pragma("unroll")                                                        \
      for (int nt = 0; nt < 8; ++nt)                                           \
        bsv[nt] = *(h16x8*)(smem + SM_R0 + ((nt * 16 + r) * 72 + ks2 * 32 + q4 * 8) * 2); \
      int ksg = (quar) * 2 + ks2;                                              \
      _Pragma("unroll")                                                        \
      for (int h = 0; h < 2; ++h) {                                            \
        int mt2 = w * 2 + h;                                                   \
        h16x8 af = *(const h16x8*)&awtP[(mt2 * 16 + r) * 256 + ksg * 32 + q4 * 8]; \
        _Pragma("unroll")                                                      \
        for (int nt = 0; nt < 8; ++nt)                                         \
          accD[h][nt] = __builtin_amdgcn_mfma_f32_16x16x32_f16(af, bsv[nt], accD[h][nt], 0, 0, 0); \
      }                                                                        \
    }                                                                          \
  }

  C_QUARTER(0)
  __syncthreads();   // C0 visible for D0
  D_QUARTER(0)
  __syncthreads();   // D0 reads done before C1 overwrites aL
  C_QUARTER(1)
  __syncthreads();
  D_QUARTER(1)
  __syncthreads();
  C_QUARTER(2)
  __syncthreads();
  D_QUARTER(2)
  __syncthreads();
  C_QUARTER(3)
  __syncthreads();
  D_QUARTER(3)
  __syncthreads();   // D3's R0 reads complete before lgc writes R0+R1

  // lgc write: 128 cols x 136 f16 over R0+R1 (hB dead after C3; aL dead)
  {
#pragma unroll
    for (int h = 0; h < 2; ++h) {
      int orr0 = (w * 2 + h) * 16 + q4 * 4;
      f32x4 ab = *(const f32x4*)&abtX[orr0];
#pragma unroll
      for (int nt = 0; nt < 8; ++nt) {
        int col = nt * 16 + r;
        if (col < QPB * KNN) {
          f32x4 vv = accD[h][nt] + ab;
          h16x4 pk = {(_Float16)vv[0], (_Float16)vv[1], (_Float16)vv[2], (_Float16)vv[3]};
          *(h16x4*)(smem + SM_LGC + (col * 136 + orr0) * 2) = pk;
        }
      }
    }
  }
  __syncthreads();   // lgc cross-wave for E

  // Phase E: lane li owns output channel o=li for both upsample rows;
  // two passes cover p = 0..5 (waves 0..3 then 0..1).
#pragma unroll 1
  for (int it = 0; it < 2; ++it) {
    int p  = (t >> 6) + it * 4;
    int li = t & 63;
    if (p < QPB && n0 + p < NPTS) {
      h16x2 Lp[KNN];
      float G[KNN];
#pragma unroll
      for (int kk = 0; kk < KNN; ++kk) {
        Lp[kk] = *(h16x2*)(smem + SM_LGC + ((p * 20 + kk) * 136 + li * 2) * 2);
        G[kk]  = (float)*(_Float16*)(smem + SM_VGB + ((p * 20 + kk) * 68 + li) * 2);
      }
#pragma unroll
      for (int half = 0; half < 2; ++half) {
        float mx = (float)Lp[0][half];
#pragma unroll
        for (int kk = 1; kk < KNN; ++kk) mx = fmaxf(mx, (float)Lp[kk][half]);
        float s = 0.f, a = 0.f;
#pragma unroll
        for (int kk = 0; kk < KNN; ++kk) {
          float e = __expf((float)Lp[kk][half] - mx);
          s += e;
          a += e * G[kk];
        }
        float rs = 1.0f / s;
        agg[(((size_t)(b * NPTS + n0 + p)) * UPF + half) * DIM + li] = a * rs;
      }
    }
  }
#undef C_QUARTER
#undef D_QUARTER
}

// ---------------------------------------------------------------------------
// out_proj (unchanged)
// ---------------------------------------------------------------------------
__global__ __launch_bounds__(256) void out_proj(const float* __restrict__ agg,
    const float* __restrict__ we, const float* __restrict__ be,
    const float* __restrict__ query, float* __restrict__ out) {
  __shared__ float A[64][65];
  const int b  = blockIdx.x >> 7;
  const int m0 = (blockIdx.x & 127) * 64;
  const int t  = threadIdx.x;
  for (int l = t; l < 64 * 64; l += 256) {
    int row = l >> 6, c = l & 63;
    A[row][c] = agg[(b * MOUT + m0 + row) * DIM + c];
  }
  __syncthreads();
  const int m_l = t & 63;
  const int w   = __builtin_amdgcn_readfirstlane(t >> 6);
  float acc[32];
#pragma unroll
  for (int i = 0; i < 32; ++i) acc[i] = 0.f;
  for (int c = 0; c < DIM; ++c) {
    float a = A[m_l][c];
#pragma unroll
    for (int i = 0; i < 32; ++i) acc[i] += we[(w * 32 + i) * DIM + c] * a;
  }
  const int m = m0 + m_l;
#pragma unroll
  for (int i = 0; i < 32; ++i) {
    int o = w * 32 + i;
    out[(b * CIN + o) * MOUT + m] = acc[i] + be[o] + query[(b * CIN + o) * NPTS + (m >> 1)];
  }
}

// ---------------------------------------------------------------------------
extern "C" void kernel_launch(void* const* d_in, const int* in_sizes, int n_in,
                              void* d_out, int out_size, void* d_ws, size_t ws_size,
                              hipStream_t stream) {
  (void)in_sizes; (void)n_in; (void)out_size; (void)ws_size;
  const float* pos1     = (const float*)d_in[0];
  const float* query    = (const float*)d_in[1];
  const float* pos2     = (const float*)d_in[2];
  const float* key_feat = (const float*)d_in[3];
  const float* wq  = (const float*)d_in[4];
  const float* bq  = (const float*)d_in[5];
  const float* wk  = (const float*)d_in[6];
  const float* bk  = (const float*)d_in[7];
  const float* wv  = (const float*)d_in[8];
  const float* bv  = (const float*)d_in[9];
  const float* pw1 = (const float*)d_in[10];
  const float* pb1 = (const float*)d_in[11];
  const float* pg  = (const float*)d_in[12];
  const float* pbt = (const float*)d_in[13];
  const float* pm  = (const float*)d_in[14];
  const float* pv  = (const float*)d_in[15];
  const float* pw2 = (const float*)d_in[16];
  const float* pb2 = (const float*)d_in[17];
  const float* aw1 = (const float*)d_in[18];
  const float* ab1 = (const float*)d_in[19];
  const float* ag  = (const float*)d_in[20];
  const float* abt2= (const float*)d_in[21];
  const float* am  = (const float*)d_in[22];
  const float* av  = (const float*)d_in[23];
  const float* awt = (const float*)d_in[24];
  const float* abt = (const float*)d_in[25];
  const float* we  = (const float*)d_in[26];
  const float* be  = (const float*)d_in[27];

  float* ws   = (float*)d_ws;
  float* q_t  = ws;
  float* k_t  = q_t + BATCH * NPTS * DIM;
  float* v_t  = k_t + BATCH * NPTS2 * DIM;
  float* aggb = v_t + BATCH * NPTS2 * DIM;
  int*   idxb = (int*)(aggb + BATCH * MOUT * DIM);
  _Float16* aw1h = (_Float16*)(idxb + BATCH * NPTS * KNN);
  _Float16* awtP = aw1h + HATT * DIM;
  _Float16* pw2h = awtP + 128 * HATT;
  float* abtX    = (float*)(pw2h + DIM * HPOS);
  float* ab1f    = abtX + 128;
  float* pw1f    = ab1f + HATT;
  float* pb1f    = pw1f + HPOS * 3;

  front<<<FB_PACK, 256, 0, stream>>>(
      pos1, pos2, idxb,
      key_feat, wk, bk, wv, bv, k_t, v_t,
      query, wq, bq, q_t,
      aw1, awt, pw2, ag, av, abt2, am, abt,
      pg, pv, pbt, pm, ab1, pb1, pw1,
      aw1h, awtP, pw2h, abtX, ab1f, pw1f, pb1f);
  attn_mfma<<<BATCH * BPB, 256, 0, stream>>>(q_t, k_t, v_t, idxb, pos1, pos2,
      pw1f, pb1f, pw2h, pb2, aw1h, ab1f, awtP, abtX, aggb);
  out_proj<<<BATCH * (MOUT / 64), 256, 0, stream>>>(aggb, we, be, query, (float*)d_out);
}

// Round 8
// 311.225 us; speedup vs baseline: 1.0461x; 1.0101x over previous
//
#include <hip/hip_runtime.h>
#include <hip/hip_bf16.h>

#define BATCH 4
#define NPTS  4096
#define NPTS2 4096
#define CIN   128
#define DIM   64
#define KNN   20
#define UPF   2
#define HPOS  64
#define HATT  256
#define MOUT  8192
#define EPSF  1e-5f
#define QPB   6            // queries per attn block
#define BPB   683          // ceil(4096/6) attn blocks per batch

// front kernel block ranges
#define FB_KNN   1024
#define FB_PKV   (FB_KNN + 256)
#define FB_PQ    (FB_PKV + 256)
#define FB_PACK  (FB_PQ + 128)

typedef _Float16 h16x8 __attribute__((ext_vector_type(8)));
typedef _Float16 h16x4 __attribute__((ext_vector_type(4)));
typedef _Float16 h16x2 __attribute__((ext_vector_type(2)));
typedef float    f32x4 __attribute__((ext_vector_type(4)));

__device__ inline float rdlane(float v, int src) {
  return __int_as_float(__builtin_amdgcn_readlane(__float_as_int(v), src));
}

// Bit-exact distance: explicit fma DAG -> identical value in every use site.
__device__ __forceinline__ float distf(float qn, float m2x, float m2y, float m2z,
                                       float x, float y, float z) {
  float s = __fmaf_rn(x, x, qn);
  s = __fmaf_rn(y, y, s);
  s = __fmaf_rn(z, z, s);
  s = __fmaf_rn(m2x, x, s);
  s = __fmaf_rn(m2y, y, s);
  s = __fmaf_rn(m2z, z, s);
  return s;
}

// ---------------------------------------------------------------------------
// front (unchanged from R15): fused {knn v5, proj_kv, proj_q, pack_weights}.
// ---------------------------------------------------------------------------
__global__ __launch_bounds__(256) void front(
    // knn
    const float* __restrict__ pos1, const float* __restrict__ pos2,
    int* __restrict__ idxout,
    // proj_kv
    const float* __restrict__ key_feat,
    const float* __restrict__ wk, const float* __restrict__ bk,
    const float* __restrict__ wv, const float* __restrict__ bv,
    float* __restrict__ k_t, float* __restrict__ v_t,
    // proj_q
    const float* __restrict__ query,
    const float* __restrict__ wq, const float* __restrict__ bq,
    float* __restrict__ q_t,
    // pack_weights
    const float* __restrict__ aw1, const float* __restrict__ awt,
    const float* __restrict__ pw2,
    const float* __restrict__ ag,  const float* __restrict__ av,
    const float* __restrict__ abt2, const float* __restrict__ am,
    const float* __restrict__ abt,
    const float* __restrict__ pg,  const float* __restrict__ pv,
    const float* __restrict__ pbt, const float* __restrict__ pm,
    const float* __restrict__ ab1, const float* __restrict__ pb1,
    const float* __restrict__ pw1,
    _Float16* __restrict__ aw1h, _Float16* __restrict__ awtP,
    _Float16* __restrict__ pw2h, float* __restrict__ abtX,
    float* __restrict__ ab1f, float* __restrict__ pw1f,
    float* __restrict__ pb1f) {
  __shared__ union {
    struct { float X[CIN][64]; float O[64][65]; } pj;
    struct { int cnt[16]; float dbuf[16][64]; int jbuf[16][64]; } kn;
  } smU;
  const int bid = blockIdx.x;
  const int t   = threadIdx.x;

  if (bid < FB_KNN) {
    // ---------------- knn v5 ----------------
    const int lane = t & 63;
    const int wv   = t >> 6;
    const int b    = bid >> 8;           // 256 blocks per batch
    const int nb   = (bid & 255) * 16;   // 16 queries per block
    const float* p2x = pos2 + (b * 3 + 0) * NPTS2;
    const float* p2y = pos2 + (b * 3 + 1) * NPTS2;
    const float* p2z = pos2 + (b * 3 + 2) * NPTS2;

    float qn[4], m2x[4], m2y[4], m2z[4];
#pragma unroll
    for (int qi = 0; qi < 4; ++qi) {
      int n = nb + wv * 4 + qi;
      float qx = pos1[(b * 3 + 0) * NPTS + n];
      float qy = pos1[(b * 3 + 1) * NPTS + n];
      float qz = pos1[(b * 3 + 2) * NPTS + n];
      qn[qi]  = qx * qx + qy * qy + qz * qz;
      m2x[qi] = -2.0f * qx; m2y[qi] = -2.0f * qy; m2z[qi] = -2.0f * qz;
    }

    float mymin[4] = {3.402823466e38f, 3.402823466e38f,
                      3.402823466e38f, 3.402823466e38f};
    f32x4 cx[4], cy[4], cz[4];
#pragma unroll 1
    for (int c = 0; c < 4; ++c) {
      int base = c * 1024 + lane * 4;
#pragma unroll
      for (int g = 0; g < 4; ++g) {
        cx[g] = *(const f32x4*)(p2x + base + g * 256);
        cy[g] = *(const f32x4*)(p2y + base + g * 256);
        cz[g] = *(const f32x4*)(p2z + base + g * 256);
      }
#pragma unroll
      for (int qi = 0; qi < 4; ++qi)
#pragma unroll
        for (int g = 0; g < 4; ++g)
#pragma unroll
          for (int e = 0; e < 4; ++e) {
            float d = distf(qn[qi], m2x[qi], m2y[qi], m2z[qi],
                            cx[g][e], cy[g][e], cz[g][e]);
            mymin[qi] = fminf(mymin[qi], d);
          }
    }

    float T0[4];
#pragma unroll
    for (int qi = 0; qi < 4; ++qi) {
      float v = mymin[qi];
#pragma unroll
      for (int k = 2; k <= 64; k <<= 1)
#pragma unroll
        for (int jj = k >> 1; jj >= 1; jj >>= 1) {
          float o = __shfl_xor(v, jj);
          bool up = ((lane & k) == 0);
          bool keepmin = (((lane & jj) == 0) == up);
          v = keepmin ? fminf(v, o) : fmaxf(v, o);
        }
      T0[qi] = rdlane(v, 19);
    }

    if (lane < 4) smU.kn.cnt[wv * 4 + lane] = 0;
    // per-wave private buffers; per-wave LDS in-order -> no barrier

#pragma unroll 1
    for (int c = 0; c < 4; ++c) {
      int base = c * 1024 + lane * 4;
#pragma unroll
      for (int g = 0; g < 4; ++g) {
        cx[g] = *(const f32x4*)(p2x + base + g * 256);
        cy[g] = *(const f32x4*)(p2y + base + g * 256);
        cz[g] = *(const f32x4*)(p2z + base + g * 256);
      }
#pragma unroll
      for (int qi = 0; qi < 4; ++qi) {
        const int qq = wv * 4 + qi;
#pragma unroll
        for (int g = 0; g < 4; ++g)
#pragma unroll
          for (int e = 0; e < 4; ++e) {
            float d = distf(qn[qi], m2x[qi], m2y[qi], m2z[qi],
                            cx[g][e], cy[g][e], cz[g][e]);
            if (d <= T0[qi]) {
              int slot = atomicAdd(&smU.kn.cnt[qq], 1);
              if (slot < 64) { smU.kn.dbuf[qq][slot] = d; smU.kn.jbuf[qq][slot] = base + g * 256 + e; }
            }
          }
      }
    }

#pragma unroll 1
    for (int qi = 0; qi < 4; ++qi) {
      const int qq = wv * 4 + qi;
      const int n  = nb + qq;
      const int cnt = smU.kn.cnt[qq];
      if (cnt <= 64) {
        float dk = (lane < cnt) ? smU.kn.dbuf[qq][lane] : 3.402823466e38f;
        int   jk = (lane < cnt) ? smU.kn.jbuf[qq][lane] : 0x7fffffff;
#pragma unroll
        for (int k = 2; k <= 64; k <<= 1) {
#pragma unroll
          for (int jj = k >> 1; jj >= 1; jj >>= 1) {
            float od = __shfl_xor(dk, jj);
            int   oj = __shfl_xor(jk, jj);
            bool mineSm = (dk < od) || (dk == od && jk < oj);
            bool up = ((lane & k) == 0);
            bool keepmin = (((lane & jj) == 0) == up);
            bool takeOther = (keepmin != mineSm);
            dk = takeOther ? od : dk;
            jk = takeOther ? oj : jk;
          }
        }
        if (lane < KNN) idxout[(b * NPTS + n) * KNN + lane] = jk;
      } else {
        float dl = 3.402823466e38f;
        int   il = 0;
        for (int j0 = 0; j0 < NPTS2; j0 += 64) {
          int j = j0 + lane;
          float d = distf(qn[qi], m2x[qi], m2y[qi], m2z[qi], p2x[j], p2y[j], p2z[j]);
          float T = rdlane(dl, 19);
          unsigned long long m = __ballot(d < T);
          while (m) {
            int src = __ffsll(m) - 1;
            m &= m - 1;
            float dd = rdlane(d, src);
            float T2 = rdlane(dl, 19);
            if (dd < T2) {
              int jj2 = j0 + src;
              float pd = __shfl_up(dl, 1);
              int   pi = __shfl_up(il, 1);
              if (dl > dd) {
                if (lane == 0 || pd <= dd) { dl = dd; il = jj2; }
                else                       { dl = pd; il = pi; }
              }
            }
          }
        }
        if (lane < KNN) idxout[(b * NPTS + n) * KNN + lane] = il;
      }
    }
  } else if (bid < FB_PKV) {
    // ---------------- proj_kv ----------------
    const int vb = bid - FB_KNN;
    const int b  = vb >> 6;
    const int n0 = (vb & 63) * 64;
    for (int l = t; l < CIN * 64; l += 256) {
      int c = l >> 6, i = l & 63;
      smU.pj.X[c][i] = key_feat[(b * CIN + c) * NPTS2 + n0 + i];
    }
    __syncthreads();
    const int n_l = t & 63;
    const int w   = __builtin_amdgcn_readfirstlane(t >> 6);
    float acck[16], accv[16];
#pragma unroll
    for (int i = 0; i < 16; ++i) { acck[i] = bk[w * 16 + i]; accv[i] = bv[w * 16 + i]; }
    for (int c = 0; c < CIN; ++c) {
      float xv = smU.pj.X[c][n_l];
#pragma unroll
      for (int i = 0; i < 16; ++i) {
        acck[i] += wk[(w * 16 + i) * CIN + c] * xv;
        accv[i] += wv[(w * 16 + i) * CIN + c] * xv;
      }
    }
#pragma unroll
    for (int i = 0; i < 16; ++i) smU.pj.O[n_l][w * 16 + i] = acck[i];
    __syncthreads();
    for (int l = t; l < 64 * 64; l += 256)
      k_t[(b * NPTS2 + n0 + (l >> 6)) * DIM + (l & 63)] = smU.pj.O[l >> 6][l & 63];
    __syncthreads();
#pragma unroll
    for (int i = 0; i < 16; ++i) smU.pj.O[n_l][w * 16 + i] = accv[i];
    __syncthreads();
    for (int l = t; l < 64 * 64; l += 256)
      v_t[(b * NPTS2 + n0 + (l >> 6)) * DIM + (l & 63)] = smU.pj.O[l >> 6][l & 63];
  } else if (bid < FB_PQ) {
    // ---------------- proj_q ----------------
    const int vb = bid - FB_PKV;
    const int b  = vb >> 6;
    const int n0 = (vb & 63) * 64;
    for (int l = t; l < CIN * 64; l += 256) {
      int c = l >> 6, i = l & 63;
      smU.pj.X[c][i] = query[(b * CIN + c) * NPTS + n0 + i];
    }
    __syncthreads();
    const int n_l = t & 63;
    const int w   = __builtin_amdgcn_readfirstlane(t >> 6);
    float acc[16];
#pragma unroll
    for (int i = 0; i < 16; ++i) acc[i] = bq[w * 16 + i];
    for (int c = 0; c < CIN; ++c) {
      float xv = smU.pj.X[c][n_l];
#pragma unroll
      for (int i = 0; i < 16; ++i) acc[i] += wq[(w * 16 + i) * CIN + c] * xv;
    }
#pragma unroll
    for (int i = 0; i < 16; ++i) smU.pj.O[n_l][w * 16 + i] = acc[i];
    __syncthreads();
    for (int l = t; l < 64 * 64; l += 256)
      q_t[(b * NPTS + n0 + (l >> 6)) * DIM + (l & 63)] = smU.pj.O[l >> 6][l & 63];
  } else {
    // ---------------- pack_weights ----------------
    int i = (bid - FB_PQ) * 256 + t;
    if (i < 16384) {
      int j = i >> 6;
      float inv = ag[j] / sqrtf(av[j] + EPSF);
      aw1h[i] = (_Float16)(aw1[i] * inv);
    }
    if (i < 32768) {
      int orr = i >> 8, j = i & 255;
      awtP[i] = (_Float16)awt[j * 128 + orr];
    }
    if (i < 4096) pw2h[i] = (_Float16)pw2[i];
    if (i < 256) {
      float inv = ag[i] / sqrtf(av[i] + EPSF);
      ab1f[i] = ab1[i] * inv + (abt2[i] - am[i] * inv);
    }
    if (i < 192) {
      int hc = i / 3;
      float inv = pg[hc] / sqrtf(pv[hc] + EPSF);
      pw1f[i] = pw1[i] * inv;
    }
    if (i < 128) abtX[i] = abt[i >> 1];
    if (i < 64) {
      float inv = pg[i] / sqrtf(pv[i] + EPSF);
      pb1f[i] = pb1[i] * inv + (pbt[i] - pm[i] * inv);
    }
  }
}

// ---------------------------------------------------------------------------
// attn_mfma (R19): R18 + aL double-buffer in LDS -> D(q) || C(q+1) overlap.
//  R18 confirmed per-phase work density is the lever (QPB 3->6 = -11us with
//  occupancy DROP). R19 halves the barrier count in C/D (8->4): hB gets its
//  own persistent arena, aL gets two buffers. Each inter-barrier region now
//  holds D(q)+C(q+1) = 48 MFMAs + LDS reads. LDS 72704 B -> 2 blocks/CU
//  (proven-free occupancy drop).
//  Hazards: aL0 last access D2 (pre-bar6), hB last read C3 (pre-bar6), D3
//  reads only aL1 -> lgc [0,34816) writes post-D3 need NO barrier (disjoint
//  from aL1; hB/aL0 quiesced by bar6). bar7 = lgc visibility for E.
//  Verify: WRITE_SIZE ~9-10MB (>30MB = spill = revert).
// LDS map: hB [0,18432) (peL -> hB in place; persists through C3);
//          h1B/aL0 [18432,36864); aL1 [36864,55296);
//          VGB [55296,72704) 128x68 f16; lgc [0,34816) post-D3.
// ---------------------------------------------------------------------------
#define SM_HB    0
#define SM_H1B   18432
#define SM_AL0   18432
#define SM_AL1   36864
#define SM_VGB   55296
#define SM_LGC   0

__global__ __launch_bounds__(256, 2) void attn_mfma(
    const float* __restrict__ q_t, const float* __restrict__ k_t,
    const float* __restrict__ v_t, const int* __restrict__ idx,
    const float* __restrict__ pos1, const float* __restrict__ pos2,
    const float* __restrict__ pw1f, const float* __restrict__ pb1f,
    const _Float16* __restrict__ pw2h, const float* __restrict__ pb2,
    const _Float16* __restrict__ aw1h, const float* __restrict__ ab1f,
    const _Float16* __restrict__ awtP, const float* __restrict__ abtX,
    float* __restrict__ agg) {
  __shared__ __align__(16) char smem[72704];
  const int b  = blockIdx.x / BPB;
  const int n0 = (blockIdx.x - b * BPB) * QPB;
  const int t  = threadIdx.x;
  const int lane = t & 63;
  const int w  = t >> 6;        // wave id
  const int r  = lane & 15;     // tile lane index
  const int q4 = lane >> 4;     // quad
  const int c0 = t & 63;        // first col; second col = c0 + 64
  const int cgB = w;            // ch-group

  // Neighbor indices for both col-halves (L1-cached idx reads)
  int  jBh[2]; bool okh[2]; int nqh[2];
#pragma unroll
  for (int hl = 0; hl < 2; ++hl) {
    int colB = c0 + hl * 64;
    int pB = colB / 20;
    okh[hl] = (pB < QPB) && (n0 + pB < NPTS);
    nqh[hl] = okh[hl] ? (n0 + pB) : 0;
    jBh[hl] = okh[hl] ? idx[(b * NPTS + nqh[hl]) * KNN + (colB - pB * 20)] : 0;
  }

  // Prefetch half-0 q/k/v (hidden under Phase 1 + A); q-k folded at load.
  f32x4 qk4[4], vv4[4];
  {
    const float* qrow = q_t + ((size_t)(b * NPTS  + nqh[0])) * DIM + cgB * 16;
    const float* krow = k_t + ((size_t)(b * NPTS2 + jBh[0])) * DIM + cgB * 16;
    const float* vrow = v_t + ((size_t)(b * NPTS2 + jBh[0])) * DIM + cgB * 16;
#pragma unroll
    for (int u = 0; u < 4; ++u) {
      f32x4 qv = *(const f32x4*)(qrow + u * 4);
      f32x4 kv = *(const f32x4*)(krow + u * 4);
      qk4[u] = qv - kv;
      vv4[u] = *(const f32x4*)(vrow + u * 4);
    }
  }

  // Phase 1: pos-MLP hidden -> h1B f16 [col][hc] stride 72 (h1B arena)
#pragma unroll
  for (int hl = 0; hl < 2; ++hl) {
    int colB = c0 + hl * 64;
    float p0 = 0.f, p1 = 0.f, p2 = 0.f;
    if (okh[hl]) {
      p0 = pos1[(b * 3 + 0) * NPTS + nqh[hl]] - pos2[(b * 3 + 0) * NPTS2 + jBh[hl]];
      p1 = pos1[(b * 3 + 1) * NPTS + nqh[hl]] - pos2[(b * 3 + 1) * NPTS2 + jBh[hl]];
      p2 = pos1[(b * 3 + 2) * NPTS + nqh[hl]] - pos2[(b * 3 + 2) * NPTS2 + jBh[hl]];
    }
#pragma unroll
    for (int hf = 0; hf < 2; ++hf) {
      h16x8 pk;
#pragma unroll
      for (int ii = 0; ii < 8; ++ii) {
        int hc = cgB * 16 + hf * 8 + ii;
        float v0 = pb1f[hc] + pw1f[hc*3] * p0 + pw1f[hc*3+1] * p1 + pw1f[hc*3+2] * p2;
        v0 = fmaxf(v0, 0.f);
        if (!okh[hl]) v0 = 0.f;
        pk[ii] = (_Float16)v0;
      }
      *(h16x8*)(smem + SM_H1B + ((colB * 72 + cgB * 16 + hf * 8) * 2)) = pk;
    }
  }
  __syncthreads();   // bar 1: h1B cross-wave for A

  // Phase A: GEMM0 pe = pw2 @ h1 (+pb2) -> peL f16 [col][o] stride 72 (hB)
  {
    f32x4 acc[8];
#pragma unroll
    for (int nt = 0; nt < 8; ++nt) acc[nt] = (f32x4){0.f, 0.f, 0.f, 0.f};
#pragma unroll
    for (int ks = 0; ks < 2; ++ks) {
      h16x8 a0 = *(const h16x8*)&pw2h[(w * 16 + r) * 64 + ks * 32 + q4 * 8];
#pragma unroll
      for (int nt = 0; nt < 8; ++nt) {
        h16x8 bv = *(h16x8*)(smem + SM_H1B + ((nt * 16 + r) * 72 + ks * 32 + q4 * 8) * 2);
        acc[nt] = __builtin_amdgcn_mfma_f32_16x16x32_f16(a0, bv, acc[nt], 0, 0, 0);
      }
    }
    int o0 = w * 16 + q4 * 4;
    f32x4 pbv = *(const f32x4*)&pb2[o0];
#pragma unroll
    for (int nt = 0; nt < 8; ++nt) {
      f32x4 vv = acc[nt] + pbv;
      h16x4 pk = {(_Float16)vv[0], (_Float16)vv[1], (_Float16)vv[2], (_Float16)vv[3]};
      *(h16x4*)(smem + SM_HB + ((nt * 16 + r) * 72 + o0) * 2) = pk;
    }
  }
  // NO barrier: wave w wrote peL ch [16w,16w+16) for ALL 128 cols; B's thread
  // (cols {c0, c0+64}, cgB=w) reads only that range. Per-wave LDS in-order.

  // Phase B: h = (q-k)+pe IN PLACE over peL (hB); vg -> vgB stride 68.
#pragma unroll 1
  for (int hl = 0; hl < 2; ++hl) {
    int colB = c0 + hl * 64;
    if (hl == 1) {
      const float* qrow = q_t + ((size_t)(b * NPTS  + nqh[1])) * DIM + cgB * 16;
      const float* krow = k_t + ((size_t)(b * NPTS2 + jBh[1])) * DIM + cgB * 16;
      const float* vrow = v_t + ((size_t)(b * NPTS2 + jBh[1])) * DIM + cgB * 16;
#pragma unroll
      for (int u = 0; u < 4; ++u) {
        f32x4 qv = *(const f32x4*)(qrow + u * 4);
        f32x4 kv = *(const f32x4*)(krow + u * 4);
        qk4[u] = qv - kv;
        vv4[u] = *(const f32x4*)(vrow + u * 4);
      }
    }
    h16x8 pe8[2];
#pragma unroll
    for (int hf = 0; hf < 2; ++hf)
      pe8[hf] = *(h16x8*)(smem + SM_HB + (colB * 72 + cgB * 16 + hf * 8) * 2);
    h16x8 hp8[2];
#pragma unroll
    for (int u = 0; u < 4; ++u) {
      int hf = u >> 1, e0 = (u & 1) * 4;
      f32x4 pe = {(float)pe8[hf][e0],     (float)pe8[hf][e0 + 1],
                  (float)pe8[hf][e0 + 2], (float)pe8[hf][e0 + 3]};
      f32x4 hv = qk4[u] + pe;
      f32x4 gv = vv4[u] + pe;
      if (!okh[hl]) { hv = (f32x4){0.f,0.f,0.f,0.f}; gv = hv; }
      hp8[hf][e0]     = (_Float16)hv[0];
      hp8[hf][e0 + 1] = (_Float16)hv[1];
      hp8[hf][e0 + 2] = (_Float16)hv[2];
      hp8[hf][e0 + 3] = (_Float16)hv[3];
      h16x4 gp = {(_Float16)gv[0], (_Float16)gv[1], (_Float16)gv[2], (_Float16)gv[3]};
      *(h16x4*)(smem + SM_VGB + (colB * 68 + cgB * 16 + u * 4) * 2) = gp;
    }
#pragma unroll
    for (int hf = 0; hf < 2; ++hf)
      *(h16x8*)(smem + SM_HB + (colB * 72 + cgB * 16 + hf * 8) * 2) = hp8[hf];
  }
  __syncthreads();   // bar 2: hB cross-wave for C; h1B dead -> aL0 reuse

  // Phases C+D over four j-quarters; aL double-buffered (AL0/AL1), hB
  // persistent. One barrier per quarter: D(q) || C(q+1) overlap.
  f32x4 accD[2][8];
#pragma unroll
  for (int h = 0; h < 2; ++h)
#pragma unroll
    for (int nt = 0; nt < 8; ++nt) accD[h][nt] = (f32x4){0.f, 0.f, 0.f, 0.f};

#define C_QUARTER(quar, albase)                                                \
  {                                                                            \
    int mt = (quar) * 4 + w;                                                   \
    f32x4 acc[8];                                                              \
    _Pragma("unroll")                                                          \
    for (int nt = 0; nt < 8; ++nt) acc[nt] = (f32x4){0.f, 0.f, 0.f, 0.f};      \
    _Pragma("unroll")                                                          \
    for (int ks = 0; ks < 2; ++ks) {                                           \
      h16x8 af = *(const h16x8*)&aw1h[(mt * 16 + r) * 64 + ks * 32 + q4 * 8];  \
      h16x8 bsv[8];                                                            \
      _Pragma("unroll")                                                        \
      for (int nt = 0; nt < 8; ++nt)                                           \
        bsv[nt] = *(h16x8*)(smem + SM_HB + ((nt * 16 + r) * 72 + ks * 32 + q4 * 8) * 2); \
      _Pragma("unroll")                                                        \
      for (int nt = 0; nt < 8; ++nt)                                           \
        acc[nt] = __builtin_amdgcn_mfma_f32_16x16x32_f16(af, bsv[nt], acc[nt], 0, 0, 0); \
    }                                                                          \
    int j0  = mt * 16 + q4 * 4;                                                \
    int jq0 = j0 - (quar) * 64;                                                \
    f32x4 b1 = *(const f32x4*)&ab1f[j0];                                       \
    _Pragma("unroll")                                                          \
    for (int nt = 0; nt < 8; ++nt) {                                           \
      int col = nt * 16 + r;                                                   \
      float v0 = fmaxf(acc[nt][0] + b1[0], 0.f);                               \
      float v1 = fmaxf(acc[nt][1] + b1[1], 0.f);                               \
      float v2 = fmaxf(acc[nt][2] + b1[2], 0.f);                               \
      float v3 = fmaxf(acc[nt][3] + b1[3], 0.f);                               \
      h16x4 pk = {(_Float16)v0, (_Float16)v1, (_Float16)v2, (_Float16)v3};     \
      *(h16x4*)(smem + (albase) + (col * 72 + jq0) * 2) = pk;                  \
    }                                                                          \
  }

#define D_QUARTER(quar, albase)                                                \
  {                                                                            \
    _Pragma("unroll")                                                          \
    for (int ks2 = 0; ks2 < 2; ++ks2) {                                        \
      h16x8 bsv[8];                                                            \
      _Pragma("unroll")                                                        \
      for (int nt = 0; nt < 8; ++nt)                                           \
        bsv[nt] = *(h16x8*)(smem + (albase) + ((nt * 16 + r) * 72 + ks2 * 32 + q4 * 8) * 2); \
      int ksg = (quar) * 2 + ks2;                                              \
      _Pragma("unroll")                                                        \
      for (int h = 0; h < 2; ++h) {                                            \
        int mt2 = w * 2 + h;                                                   \
        h16x8 af = *(const h16x8*)&awtP[(mt2 * 16 + r) * 256 + ksg * 32 + q4 * 8]; \
        _Pragma("unroll")                                                      \
        for (int nt = 0; nt < 8; ++nt)                                         \
          accD[h][nt] = __builtin_amdgcn_mfma_f32_16x16x32_f16(af, bsv[nt], accD[h][nt], 0, 0, 0); \
      }                                                                        \
    }                                                                          \
  }

  C_QUARTER(0, SM_AL0)
  __syncthreads();   // bar 3: C0 visible for D0
  D_QUARTER(0, SM_AL0)
  C_QUARTER(1, SM_AL1)
  __syncthreads();   // bar 4: C1 visible; D0's AL0 reads done pre-C2
  D_QUARTER(1, SM_AL1)
  C_QUARTER(2, SM_AL0)
  __syncthreads();   // bar 5: C2 visible; D1's AL1 reads done pre-C3
  D_QUARTER(2, SM_AL0)
  C_QUARTER(3, SM_AL1)
  __syncthreads();   // bar 6: C3 visible; D2's AL0 reads done; hB reads done
  D_QUARTER(3, SM_AL1)

  // lgc write: [0,34816) overlays hB+aL0 -- both quiesced by bar 6; D3
  // concurrently reads only AL1 [36864,55296) -> disjoint, no barrier needed.
  {
#pragma unroll
    for (int h = 0; h < 2; ++h) {
      int orr0 = (w * 2 + h) * 16 + q4 * 4;
      f32x4 ab = *(const f32x4*)&abtX[orr0];
#pragma unroll
      for (int nt = 0; nt < 8; ++nt) {
        int col = nt * 16 + r;
        if (col < QPB * KNN) {
          f32x4 vv = accD[h][nt] + ab;
          h16x4 pk = {(_Float16)vv[0], (_Float16)vv[1], (_Float16)vv[2], (_Float16)vv[3]};
          *(h16x4*)(smem + SM_LGC + (col * 136 + orr0) * 2) = pk;
        }
      }
    }
  }
  __syncthreads();   // bar 7: lgc cross-wave for E

  // Phase E: lane li owns output channel o=li for both upsample rows;
  // two passes cover p = 0..5 (waves 0..3 then 0..1).
#pragma unroll 1
  for (int it = 0; it < 2; ++it) {
    int p  = (t >> 6) + it * 4;
    int li = t & 63;
    if (p < QPB && n0 + p < NPTS) {
      h16x2 Lp[KNN];
      float G[KNN];
#pragma unroll
      for (int kk = 0; kk < KNN; ++kk) {
        Lp[kk] = *(h16x2*)(smem + SM_LGC + ((p * 20 + kk) * 136 + li * 2) * 2);
        G[kk]  = (float)*(_Float16*)(smem + SM_VGB + ((p * 20 + kk) * 68 + li) * 2);
      }
#pragma unroll
      for (int half = 0; half < 2; ++half) {
        float mx = (float)Lp[0][half];
#pragma unroll
        for (int kk = 1; kk < KNN; ++kk) mx = fmaxf(mx, (float)Lp[kk][half]);
        float s = 0.f, a = 0.f;
#pragma unroll
        for (int kk = 0; kk < KNN; ++kk) {
          float e = __expf((float)Lp[kk][half] - mx);
          s += e;
          a += e * G[kk];
        }
        float rs = 1.0f / s;
        agg[(((size_t)(b * NPTS + n0 + p)) * UPF + half) * DIM + li] = a * rs;
      }
    }
  }
#undef C_QUARTER
#undef D_QUARTER
}

// ---------------------------------------------------------------------------
// out_proj (unchanged)
// ---------------------------------------------------------------------------
__global__ __launch_bounds__(256) void out_proj(const float* __restrict__ agg,
    const float* __restrict__ we, const float* __restrict__ be,
    const float* __restrict__ query, float* __restrict__ out) {
  __shared__ float A[64][65];
  const int b  = blockIdx.x >> 7;
  const int m0 = (blockIdx.x & 127) * 64;
  const int t  = threadIdx.x;
  for (int l = t; l < 64 * 64; l += 256) {
    int row = l >> 6, c = l & 63;
    A[row][c] = agg[(b * MOUT + m0 + row) * DIM + c];
  }
  __syncthreads();
  const int m_l = t & 63;
  const int w   = __builtin_amdgcn_readfirstlane(t >> 6);
  float acc[32];
#pragma unroll
  for (int i = 0; i < 32; ++i) acc[i] = 0.f;
  for (int c = 0; c < DIM; ++c) {
    float a = A[m_l][c];
#pragma unroll
    for (int i = 0; i < 32; ++i) acc[i] += we[(w * 32 + i) * DIM + c] * a;
  }
  const int m = m0 + m_l;
#pragma unroll
  for (int i = 0; i < 32; ++i) {
    int o = w * 32 + i;
    out[(b * CIN + o) * MOUT + m] = acc[i] + be[o] + query[(b * CIN + o) * NPTS + (m >> 1)];
  }
}

// ---------------------------------------------------------------------------
extern "C" void kernel_launch(void* const* d_in, const int* in_sizes, int n_in,
                              void* d_out, int out_size, void* d_ws, size_t ws_size,
                              hipStream_t stream) {
  (void)in_sizes; (void)n_in; (void)out_size; (void)ws_size;
  const float* pos1     = (const float*)d_in[0];
  const float* query    = (const float*)d_in[1];
  const float* pos2     = (const float*)d_in[2];
  const float* key_feat = (const float*)d_in[3];
  const float* wq  = (const float*)d_in[4];
  const float* bq  = (const float*)d_in[5];
  const float* wk  = (const float*)d_in[6];
  const float* bk  = (const float*)d_in[7];
  const float* wv  = (const float*)d_in[8];
  const float* bv  = (const float*)d_in[9];
  const float* pw1 = (const float*)d_in[10];
  const float* pb1 = (const float*)d_in[11];
  const float* pg  = (const float*)d_in[12];
  const float* pbt = (const float*)d_in[13];
  const float* pm  = (const float*)d_in[14];
  const float* pv  = (const float*)d_in[15];
  const float* pw2 = (const float*)d_in[16];
  const float* pb2 = (const float*)d_in[17];
  const float* aw1 = (const float*)d_in[18];
  const float* ab1 = (const float*)d_in[19];
  const float* ag  = (const float*)d_in[20];
  const float* abt2= (const float*)d_in[21];
  const float* am  = (const float*)d_in[22];
  const float* av  = (const float*)d_in[23];
  const float* awt = (const float*)d_in[24];
  const float* abt = (const float*)d_in[25];
  const float* we  = (const float*)d_in[26];
  const float* be  = (const float*)d_in[27];

  float* ws   = (float*)d_ws;
  float* q_t  = ws;
  float* k_t  = q_t + BATCH * NPTS * DIM;
  float* v_t  = k_t + BATCH * NPTS2 * DIM;
  float* aggb = v_t + BATCH * NPTS2 * DIM;
  int*   idxb = (int*)(aggb + BATCH * MOUT * DIM);
  _Float16* aw1h = (_Float16*)(idxb + BATCH * NPTS * KNN);
  _Float16* awtP = aw1h + HATT * DIM;
  _Float16* pw2h = awtP + 128 * HATT;
  float* abtX    = (float*)(pw2h + DIM * HPOS);
  float* ab1f    = abtX + 128;
  float* pw1f    = ab1f + HATT;
  float* pb1f    = pw1f + HPOS * 3;

  front<<<FB_PACK, 256, 0, stream>>>(
      pos1, pos2, idxb,
      key_feat, wk, bk, wv, bv, k_t, v_t,
      query, wq, bq, q_t,
      aw1, awt, pw2, ag, av, abt2, am, abt,
      pg, pv, pbt, pm, ab1, pb1, pw1,
      aw1h, awtP, pw2h, abtX, ab1f, pw1f, pb1f);
  attn_mfma<<<BATCH * BPB, 256, 0, stream>>>(q_t, k_t, v_t, idxb, pos1, pos2,
      pw1f, pb1f, pw2h, pb2, aw1h, ab1f, awtP, abtX, aggb);
  out_proj<<<BATCH * (MOUT / 64), 256, 0, stream>>>(aggb, we, be, query, (float*)d_out);
}